// Round 1
// baseline (106.455 us; speedup 1.0000x reference)
//
#include <hip/hip_runtime.h>
#include <stdint.h>

// SpottingLoss: B=2048 batches, N=64 slots, F=19 features.
// Reference: two-phase greedy bipartite matching (lax.scan, length 64 each)
// then permuted YOLO-ish loss summed over ALL axes -> single float output.
//
// Exactness argument:
//  - alpha in {0.0,1.0}; v,h stay exactly {0.0,1.0}; D2 = D1 * (0/1 factors),
//    so masking D1 (fp32, 1 - |x-p|, bit-identical to numpy) by the current
//    column-active bitmask reproduces D2 values bitwise.
//  - jnp.argmax ties -> first index. Row scan uses strict '>' over masked
//    values. Column argmax uses packed key (val_bits<<6 | (63-row)):
//    monotone in val (val>0), larger 63-row == smaller row == first index.
//    All-zero column -> winner row 0, reproduced by key init (val=0,row=0)=63.
//  - Dead rows (v=0) only ever contribute zeros downstream; their jmax is
//    irrelevant (proved: mval = v*best = 0, matched requires v=1).
//  - Early exit when ballot(v)==0: all remaining scan steps are no-ops (E==0).

#define NN 64
#define NF 19

__global__ __launch_bounds__(64) void spotting_loss_kernel(
    const float* __restrict__ yt, const float* __restrict__ yp,
    float* __restrict__ out)
{
  const int b = blockIdx.x;
  const int i = threadIdx.x;  // row index == lane (one wave per block)
  const float* __restrict__ ytb = yt + (size_t)b * NN * NF;
  const float* __restrict__ ypb = yp + (size_t)b * NN * NF;

  __shared__ float p_sh[NN];
  __shared__ unsigned long long key_sh[NN];

  const float alpha = ytb[i * NF + 0];
  const float x     = ytb[i * NF + 1];
  p_sh[i] = ypb[i * NF + 1];
  __syncthreads();

  // D1 row in registers (fully unrolled, constant indices only).
  float D1r[NN];
#pragma unroll
  for (int j = 0; j < NN; ++j) {
    D1r[j] = 1.0f - fabsf(x - p_sh[j]);
  }

  unsigned long long hbits = ~0ull;  // column j active <=> bit j set
  int   perm  = 0;                   // matched column (argmax of zero row -> 0)
  int   jmax  = 0;
  float best  = 0.0f;

  for (int phase = 0; phase < 2; ++phase) {
    // phase 0: v0 = alpha ; phase 1: v0 = 1-alpha (neg rows untouched by ph.0)
    bool vlive  = (phase == 0) ? (alpha > 0.5f) : (alpha < 0.5f);
    bool rescan = vlive;

    for (int it = 0; it < NN; ++it) {
      if (__ballot(vlive) == 0ull) break;  // remaining steps are no-ops

      if (rescan) {
        // first-index argmax over D1 masked by active columns
        const unsigned hlo = (unsigned)hbits;
        const unsigned hhi = (unsigned)(hbits >> 32);
        best = -1.0f; jmax = 0;
#pragma unroll
        for (int j = 0; j < NN; ++j) {
          const unsigned bit = (j < 32) ? ((hlo >> j) & 1u)
                                        : ((hhi >> (j - 32)) & 1u);
          const unsigned msk = 0u - bit;  // 0xFFFFFFFF or 0
          const float t = __uint_as_float(__float_as_uint(D1r[j]) & msk);
          if (t > best) { best = t; jmax = j; }
        }
        rescan = false;
      }

      key_sh[i] = 63ull;  // (val=0, row=0) baseline: zero column -> winner 0
      __syncthreads();

      if (vlive && best > 0.0f) {
        const unsigned long long key =
            (((unsigned long long)__float_as_uint(best)) << 6) |
            (unsigned long long)(63 - i);
        atomicMax(&key_sh[jmax], key);
      }
      __syncthreads();

      // column side (lane i == column i): any positive write <=> one match
      const unsigned long long kc = key_sh[i];
      const bool colkill = (kc >> 6) != 0ull;
      const unsigned long long killed = __ballot(colkill);

      if (vlive) {
        const unsigned long long kw = key_sh[jmax];
        const int winner = 63 - (int)(kw & 63ull);
        if (winner == i) {            // mutual match: Permut[i][jmax] = 1
          perm = jmax;
          vlive = false;
        } else if ((killed >> jmax) & 1ull) {
          rescan = true;              // favorite column taken by another row
        }
      }
      hbits &= ~killed;
      __syncthreads();
    }
  }

  // ----- loss -----
  const float* __restrict__ ypr = ypb + (size_t)perm * NF;
  const float a  = alpha;
  const float p0 = ypr[0];
  const float p1 = ypr[1];
  const float dx = x - p1;
  const float da = a - p0;
  float s2 = 0.0f;
#pragma unroll
  for (int f = 2; f < NF; ++f) {
    const float d = ytb[i * NF + f] - ypr[f];
    s2 += d * d;
  }
  float l = a * 5.0f * (dx * dx)
          + a * (da * da)
          + (1.0f - a) * 0.5f * (da * da)
          + a * s2;

  // wave-64 reduction, one atomic per block
#pragma unroll
  for (int off = 32; off > 0; off >>= 1) l += __shfl_down(l, off);
  if (i == 0) atomicAdd(out, l);
}

extern "C" void kernel_launch(void* const* d_in, const int* in_sizes, int n_in,
                              void* d_out, int out_size, void* d_ws, size_t ws_size,
                              hipStream_t stream) {
  const float* yt = (const float*)d_in[0];
  const float* yp = (const float*)d_in[1];
  float* out = (float*)d_out;
  const int B = in_sizes[0] / (NN * NF);

  // harness poisons d_out with 0xAA before every timed replay
  hipMemsetAsync(out, 0, sizeof(float) * (size_t)out_size, stream);
  spotting_loss_kernel<<<B, 64, 0, stream>>>(yt, yp, out);
}